// Round 4
// baseline (300.424 us; speedup 1.0000x reference)
//
#include <hip/hip_runtime.h>
#include <hip/hip_bf16.h>
#include <hip/hip_cooperative_groups.h>
#include <math.h>

namespace cg = cooperative_groups;

// Problem: B=16, T=2048, D=256, gamma=0.9
// out[b,t,d] = S2[t,d] * (x@Wq)[b,t,d]
// S2[t,d] = S[8d + (t>>8)][t&255]   (reshape-scramble)
// S[t>=1] = A[t], S[0] = A[1],  A[t] = gamma*A[t-1] + g[t], A[0]=0 (g[0] := 0)
// g = y @ Wk,  y[t,:] = sum_b w[b,t]*x[b,t,:],  w[b,t] = x[b,t,:] . rowsum(Wv)

#define GAMMA_F 0.9f
#define T_LEN 2048
#define D_DIM 256
#define B_DIM 16

typedef __attribute__((ext_vector_type(8))) short bf16x8;
typedef __attribute__((ext_vector_type(16))) float f32x16;

__device__ inline ushort f2bf(float f) {
    union { float f; unsigned u; } v; v.f = f;
    unsigned r = (v.u + 0x7FFFu + ((v.u >> 16) & 1u)) >> 16;  // RNE
    return (ushort)r;
}

// ======================= MEGA (cooperative) =======================
// 256 blocks x 1024 threads. Phases separated by grid.sync().
__global__ __launch_bounds__(1024) void k_mega(
        const float* __restrict__ x, const float* __restrict__ Wq,
        const float* __restrict__ Wk, const float* __restrict__ Wv,
        float* __restrict__ out,
        ushort* __restrict__ WqT, ushort* __restrict__ WkT,
        float* __restrict__ wv_sum, ushort* __restrict__ ybf,
        ushort* __restrict__ xbf, float* __restrict__ g,
        float* __restrict__ loc, float* __restrict__ carry,
        float* __restrict__ S2) {
    cg::grid_group grid = cg::this_grid();
    int bid = blockIdx.x, tid = threadIdx.x;
    __shared__ float red[4][B_DIM][4];

    // ---- P0: weight prep: wv_sum, WqT/WkT (bf16, [n][k]) ----
    if (bid == 0 && tid < 256) {
        const float4* row4 = (const float4*)(Wv + (size_t)tid * D_DIM);
        float s = 0.f;
#pragma unroll
        for (int i = 0; i < 64; ++i) {
            float4 v = row4[i];
            s += v.x + v.y + v.z + v.w;
        }
        wv_sum[tid] = s;
    } else if (bid >= 1 && bid < 9) {
        int half = (bid - 1) >> 2;           // 0: Wq, 1: Wk
        const float* W = half ? Wk : Wq;
        ushort* WT = half ? WkT : WqT;
        int gth = ((bid - 1) & 3) * 1024 + tid;   // 0..4095
        int n = gth >> 4, k0 = (gth & 15) * 16;
        ushort tmp[16];
#pragma unroll
        for (int i = 0; i < 16; ++i) tmp[i] = f2bf(W[(size_t)(k0 + i) * D_DIM + n]);
#pragma unroll
        for (int i = 0; i < 4; ++i)
            *(ushort4*)&WT[(size_t)n * D_DIM + k0 + i * 4] = *(ushort4*)&tmp[i * 4];
    }
    grid.sync();

    // ---- P1: y (bf16) + xbf ----
    {
        int sub = tid >> 8, d = tid & 255, lane = tid & 63, wv = (tid >> 6) & 3;
        float wvd = wv_sum[d];
#pragma unroll
        for (int it = 0; it < 2; ++it) {
            int t = it * 1024 + bid * 4 + sub;
            float xr[B_DIM];
#pragma unroll
            for (int b = 0; b < B_DIM; ++b)
                xr[b] = x[((size_t)b * T_LEN + t) * D_DIM + d];
#pragma unroll
            for (int b = 0; b < B_DIM; ++b)
                xbf[((size_t)b * T_LEN + t) * D_DIM + d] = f2bf(xr[b]);
#pragma unroll
            for (int b = 0; b < B_DIM; ++b) {
                float p = xr[b] * wvd;
                for (int o = 32; o > 0; o >>= 1) p += __shfl_down(p, o, 64);
                if (lane == 0) red[sub][b][wv] = p;
            }
            __syncthreads();
            float yv = 0.f;
#pragma unroll
            for (int b = 0; b < B_DIM; ++b) {
                float wb = red[sub][b][0] + red[sub][b][1] + red[sub][b][2] + red[sub][b][3];
                yv += wb * xr[b];
            }
            ybf[(size_t)t * D_DIM + d] = f2bf(yv);
            __syncthreads();
        }
    }
    grid.sync();

    // ---- P2: g = ybf @ WkT^T  (direct-global MFMA, 64x64 tile, waves 0..3) ----
    if (bid < 128 && tid < 256) {
        int w = tid >> 6, lane = tid & 63;
        int mt = bid >> 2, nt = bid & 3;
        int wr = w >> 1, wc = w & 1, l31 = lane & 31, lh = lane >> 5;
        f32x16 acc;
#pragma unroll
        for (int e = 0; e < 16; ++e) acc[e] = 0.f;
        const ushort* abase = ybf + (size_t)(mt * 64 + wr * 32 + l31) * D_DIM + lh * 8;
        const ushort* bbase = WkT + (size_t)(nt * 64 + wc * 32 + l31) * D_DIM + lh * 8;
#pragma unroll
        for (int s = 0; s < 16; ++s) {
            bf16x8 a = *(const bf16x8*)(abase + s * 16);
            bf16x8 b = *(const bf16x8*)(bbase + s * 16);
            acc = __builtin_amdgcn_mfma_f32_32x32x16_bf16(a, b, acc, 0, 0, 0);
        }
#pragma unroll
        for (int reg = 0; reg < 16; ++reg) {
            int rr = (reg & 3) + 8 * (reg >> 2) + 4 * lh;
            g[(size_t)(mt * 64 + wr * 32 + rr) * D_DIM + nt * 64 + wc * 32 + l31] = acc[reg];
        }
    }
    grid.sync();

    // ---- P3: local scan, 256 chunks of 8 ----
    if (tid < 256) {
        int c = bid, d = tid;
        float v[8];
#pragma unroll
        for (int j = 0; j < 8; ++j) {
            int t = c * 8 + j;
            v[j] = (t == 0) ? 0.f : g[(size_t)t * D_DIM + d];
        }
        float acc = 0.f;
#pragma unroll
        for (int j = 0; j < 8; ++j) {
            acc = GAMMA_F * acc + v[j];
            loc[(size_t)(c * 8 + j) * D_DIM + d] = acc;
        }
        carry[(size_t)c * D_DIM + d] = acc;
    }
    grid.sync();

    // ---- P4: A[t]=loc+gamma^(o+1)*P[c] (P truncated to 32 terms); scatter to S2 ----
    {
        int sub = tid >> 8, r = tid & 255;
        const float g8 = 0.43046721f;               // 0.9^8
        const float log2g = -0.15200309344504995f;  // log2(0.9)
#pragma unroll
        for (int it = 0; it < 2; ++it) {
            int tp = it * 1024 + bid * 4 + sub;
            int src = (tp == 0) ? 1 : tp;
            int c = src >> 3, o = src & 7;
            int j0 = c - 32; if (j0 < 0) j0 = 0;
            float p = 0.f;
            for (int j = j0; j < c; ++j)
                p = p * g8 + carry[(size_t)j * D_DIM + r];
            float gp = exp2f((float)(o + 1) * log2g);
            float Aval = loc[(size_t)src * D_DIM + r] + gp * p;
            S2[(size_t)(((tp & 7) << 8) + r) * D_DIM + (tp >> 3)] = Aval;
        }
    }
    grid.sync();

    // ---- P5: out = (xbf @ WqT^T) * S2.  mb=bid, 16 waves as 4x4, nb-loop. ----
    {
        int w = tid >> 6, lane = tid & 63;
        int wr = w >> 2, wc = w & 3, l31 = lane & 31, lh = lane >> 5;
        int mb = bid;
        int t_base = (mb & 15) * 128;
        const ushort* abase = xbf + (size_t)(mb * 128 + wr * 32 + l31) * D_DIM + lh * 8;
        bf16x8 afr[16];
#pragma unroll
        for (int s = 0; s < 16; ++s) afr[s] = *(const bf16x8*)(abase + s * 16);
#pragma unroll
        for (int nb = 0; nb < 2; ++nb) {
            const ushort* bbase = WqT + (size_t)(nb * 128 + wc * 32 + l31) * D_DIM + lh * 8;
            f32x16 acc;
#pragma unroll
            for (int e = 0; e < 16; ++e) acc[e] = 0.f;
#pragma unroll
            for (int s = 0; s < 16; ++s) {
                bf16x8 b = *(const bf16x8*)(bbase + s * 16);
                acc = __builtin_amdgcn_mfma_f32_32x32x16_bf16(afr[s], b, acc, 0, 0, 0);
            }
            int gn = nb * 128 + wc * 32 + l31;
#pragma unroll
            for (int reg = 0; reg < 16; ++reg) {
                int rr = (reg & 3) + 8 * (reg >> 2) + 4 * lh;
                int m = wr * 32 + rr;
                float s2v = S2[(size_t)(t_base + m) * D_DIM + gn];
                out[((size_t)mb * 128 + m) * D_DIM + gn] = acc[reg] * s2v;
            }
        }
    }
}

// ======================= FALLBACK (proven R3 path) =======================
__global__ __launch_bounds__(256) void k_prep(const float* __restrict__ Wq,
                                              const float* __restrict__ Wk,
                                              const float* __restrict__ Wv,
                                              ushort* __restrict__ WqT,
                                              ushort* __restrict__ WkT,
                                              float* __restrict__ wv_sum) {
    int bid = blockIdx.x;
    int tid = threadIdx.x;
    if (bid < 32) {
        __shared__ float tile[64][68];
        const float* W = (bid < 16) ? Wq : Wk;
        ushort* WT = (bid < 16) ? WqT : WkT;
        int b = bid & 15;
        int k0 = (b & 3) * 64;
        int n0 = (b >> 2) * 64;
        int r = tid >> 4;
        int c4 = (tid & 15) * 4;
#pragma unroll
        for (int i = 0; i < 4; ++i) {
            float4 v = *(const float4*)(W + (size_t)(k0 + r + 16 * i) * D_DIM + n0 + c4);
            *(float4*)&tile[r + 16 * i][c4] = v;
        }
        __syncthreads();
        int n = tid >> 2;
        int j0 = (tid & 3) * 16;
        ushort tmp[16];
#pragma unroll
        for (int i = 0; i < 16; ++i) tmp[i] = f2bf(tile[j0 + i][n]);
        ushort* dst = WT + (size_t)(n0 + n) * D_DIM + k0 + j0;
#pragma unroll
        for (int i = 0; i < 16; ++i) dst[i] = tmp[i];
    } else {
        int j = (bid - 32) * 64 + (tid >> 2);
        int q = tid & 3;
        const float4* row4 = (const float4*)(Wv + (size_t)j * D_DIM + q * 64);
        float s = 0.f;
#pragma unroll
        for (int i = 0; i < 16; ++i) {
            float4 v = row4[i];
            s += v.x + v.y + v.z + v.w;
        }
        s += __shfl_xor(s, 1, 64);
        s += __shfl_xor(s, 2, 64);
        if (q == 0) wv_sum[j] = s;
    }
}

__global__ __launch_bounds__(256) void k_y(const float* __restrict__ x,
                                           const float* __restrict__ wv_sum,
                                           ushort* __restrict__ ybf,
                                           ushort* __restrict__ xbf) {
    int t = blockIdx.x;
    int d = threadIdx.x;
    float wvd = wv_sum[d];
    float xr[B_DIM];
#pragma unroll
    for (int b = 0; b < B_DIM; ++b)
        xr[b] = x[((size_t)b * T_LEN + t) * D_DIM + d];
#pragma unroll
    for (int b = 0; b < B_DIM; ++b)
        xbf[((size_t)b * T_LEN + t) * D_DIM + d] = f2bf(xr[b]);

    __shared__ float red[B_DIM][4];
    int wave = d >> 6, lane = d & 63;
#pragma unroll
    for (int b = 0; b < B_DIM; ++b) {
        float p = xr[b] * wvd;
        for (int o = 32; o > 0; o >>= 1) p += __shfl_down(p, o, 64);
        if (lane == 0) red[b][wave] = p;
    }
    __syncthreads();
    float yv = 0.f;
#pragma unroll
    for (int b = 0; b < B_DIM; ++b) {
        float wb = red[b][0] + red[b][1] + red[b][2] + red[b][3];
        yv += wb * xr[b];
    }
    ybf[(size_t)t * D_DIM + d] = f2bf(yv);
}

__global__ __launch_bounds__(256) void k_gmm(const ushort* __restrict__ ybf,
                                             const ushort* __restrict__ WkT,
                                             float* __restrict__ g) {
    int mt = blockIdx.x >> 2;
    int nt = blockIdx.x & 3;
    int tid = threadIdx.x, lane = tid & 63, w = tid >> 6;
    int wr = w >> 1, wc = w & 1, l31 = lane & 31, lh = lane >> 5;
    f32x16 acc;
#pragma unroll
    for (int e = 0; e < 16; ++e) acc[e] = 0.f;
    const ushort* abase = ybf + (size_t)(mt * 64 + wr * 32 + l31) * D_DIM + lh * 8;
    const ushort* bbase = WkT + (size_t)(nt * 64 + wc * 32 + l31) * D_DIM + lh * 8;
#pragma unroll
    for (int s = 0; s < 16; ++s) {
        bf16x8 a = *(const bf16x8*)(abase + s * 16);
        bf16x8 b = *(const bf16x8*)(bbase + s * 16);
        acc = __builtin_amdgcn_mfma_f32_32x32x16_bf16(a, b, acc, 0, 0, 0);
    }
#pragma unroll
    for (int reg = 0; reg < 16; ++reg) {
        int rr = (reg & 3) + 8 * (reg >> 2) + 4 * lh;
        g[(size_t)(mt * 64 + wr * 32 + rr) * D_DIM + nt * 64 + wc * 32 + l31] = acc[reg];
    }
}

__global__ void k_scanA(const float* __restrict__ g, float* __restrict__ loc,
                        float* __restrict__ carry) {
    int c = blockIdx.x;      // 0..255, chunk of 8
    int d = threadIdx.x;
    float v[8];
#pragma unroll
    for (int j = 0; j < 8; ++j) {
        int t = c * 8 + j;
        v[j] = (t == 0) ? 0.f : g[(size_t)t * D_DIM + d];
    }
    float acc = 0.f;
#pragma unroll
    for (int j = 0; j < 8; ++j) {
        acc = GAMMA_F * acc + v[j];
        loc[(size_t)(c * 8 + j) * D_DIM + d] = acc;
    }
    carry[(size_t)c * D_DIM + d] = acc;
}

__global__ __launch_bounds__(256) void k_S2P(const float* __restrict__ loc,
                                             const float* __restrict__ carry,
                                             float* __restrict__ S2) {
    int tp = blockIdx.x;
    int r = threadIdx.x;
    int src = (tp == 0) ? 1 : tp;
    int c = src >> 3, o = src & 7;
    const float g8 = 0.43046721f;
    int j0 = c - 32; if (j0 < 0) j0 = 0;
    float p = 0.f;
    for (int j = j0; j < c; ++j)
        p = p * g8 + carry[(size_t)j * D_DIM + r];
    const float log2g = -0.15200309344504995f;
    float gp = exp2f((float)(o + 1) * log2g);
    float Aval = loc[(size_t)src * D_DIM + r] + gp * p;
    int trow = ((tp & 7) << 8) + r;
    int dcol = tp >> 3;
    S2[(size_t)trow * D_DIM + dcol] = Aval;
}

__global__ __launch_bounds__(256) void k_qgemm(const ushort* __restrict__ xbf,
                                               const ushort* __restrict__ WqT,
                                               const float* __restrict__ S2,
                                               float* __restrict__ out) {
    int bid = blockIdx.x;
    int mb = bid >> 1;
    int nb = bid & 1;
    int tid = threadIdx.x;
    int lane = tid & 63, w = tid >> 6;
    int wr = w >> 1, wc = w & 1, l31 = lane & 31, lh = lane >> 5;
    f32x16 acc[2][2];
#pragma unroll
    for (int i = 0; i < 2; ++i)
#pragma unroll
        for (int j = 0; j < 2; ++j)
#pragma unroll
            for (int e = 0; e < 16; ++e) acc[i][j][e] = 0.f;
#pragma unroll
    for (int s = 0; s < 16; ++s) {
        const ushort* ab = xbf + (size_t)(mb * 128 + wr * 64 + l31) * D_DIM + s * 16 + lh * 8;
        const ushort* bb = WqT + (size_t)(nb * 128 + wc * 64 + l31) * D_DIM + s * 16 + lh * 8;
        bf16x8 a0 = *(const bf16x8*)ab;
        bf16x8 a1 = *(const bf16x8*)(ab + 32 * D_DIM);
        bf16x8 b0 = *(const bf16x8*)bb;
        bf16x8 b1 = *(const bf16x8*)(bb + 32 * D_DIM);
        acc[0][0] = __builtin_amdgcn_mfma_f32_32x32x16_bf16(a0, b0, acc[0][0], 0, 0, 0);
        acc[0][1] = __builtin_amdgcn_mfma_f32_32x32x16_bf16(a0, b1, acc[0][1], 0, 0, 0);
        acc[1][0] = __builtin_amdgcn_mfma_f32_32x32x16_bf16(a1, b0, acc[1][0], 0, 0, 0);
        acc[1][1] = __builtin_amdgcn_mfma_f32_32x32x16_bf16(a1, b1, acc[1][1], 0, 0, 0);
    }
    int t_base = (mb & 15) * 128;
    size_t row_base = (size_t)mb * 128;
#pragma unroll
    for (int mi = 0; mi < 2; ++mi) {
#pragma unroll
        for (int ni = 0; ni < 2; ++ni) {
            int gn = nb * 128 + wc * 64 + ni * 32 + l31;
#pragma unroll
            for (int reg = 0; reg < 16; ++reg) {
                int rr = (reg & 3) + 8 * (reg >> 2) + 4 * lh;
                int m = wr * 64 + mi * 32 + rr;
                float s2v = S2[(size_t)(t_base + m) * D_DIM + gn];
                out[(row_base + m) * D_DIM + gn] = acc[mi][ni][reg] * s2v;
            }
        }
    }
}

extern "C" void kernel_launch(void* const* d_in, const int* in_sizes, int n_in,
                              void* d_out, int out_size, void* d_ws, size_t ws_size,
                              hipStream_t stream) {
    const float* x  = (const float*)d_in[0];
    const float* Wq = (const float*)d_in[1];
    const float* Wk = (const float*)d_in[2];
    const float* Wv = (const float*)d_in[3];
    float* out = (float*)d_out;

    // workspace layout
    float* ws = (float*)d_ws;
    float* g      = ws;                        // 524288 f
    float* loc    = g + 524288;                // 524288 f
    float* S2     = loc + 524288;              // 524288 f
    float* wv_sum = S2 + 524288;               // 256 f
    float* carry  = wv_sum + 256;              // 65536 f (256 chunks x 256)
    ushort* WqT   = (ushort*)(carry + 65536);  // 65536 us
    ushort* WkT   = WqT + 65536;               // 65536 us
    ushort* ybf   = WkT + 65536;               // 524288 us
    ushort* xbf   = ybf + 524288;              // 8388608 us

    void* args[] = {(void*)&x, (void*)&Wq, (void*)&Wk, (void*)&Wv, (void*)&out,
                    (void*)&WqT, (void*)&WkT, (void*)&wv_sum, (void*)&ybf,
                    (void*)&xbf, (void*)&g, (void*)&loc, (void*)&carry, (void*)&S2};
    hipError_t e = hipLaunchCooperativeKernel((void*)k_mega, dim3(256), dim3(1024),
                                              args, 0, stream);
    if (e != hipSuccess) {
        // fallback: proven multi-kernel path
        k_prep<<<36, 256, 0, stream>>>(Wq, Wk, Wv, WqT, WkT, wv_sum);
        k_y<<<T_LEN, 256, 0, stream>>>(x, wv_sum, ybf, xbf);
        k_gmm<<<128, 256, 0, stream>>>(ybf, WkT, g);
        k_scanA<<<256, 256, 0, stream>>>(g, loc, carry);
        k_S2P<<<T_LEN, 256, 0, stream>>>(loc, carry, S2);
        k_qgemm<<<(B_DIM * T_LEN / 128) * 2, 256, 0, stream>>>(xbf, WqT, S2, out);
    }
}

// Round 5
// 130.826 us; speedup vs baseline: 2.2964x; 2.2964x over previous
//
#include <hip/hip_runtime.h>
#include <hip/hip_bf16.h>
#include <math.h>

// Problem: B=16, T=2048, D=256, gamma=0.9
// out[b,t,d] = S2[t,d] * (x@Wq)[b,t,d]
// S2[t,d] = S[8d + (t>>8)][t&255]   (reshape-scramble)
// S[t>=1] = A[t], S[0] = A[1],  A[t] = gamma*A[t-1] + g[t], A[0]=0 (g[0] := 0)
// g = y @ Wk,  y[t,:] = sum_b w[b,t]*x[b,t,:],  w[b,t] = x[b,t,:] . rowsum(Wv)
//
// R5: proven R3 multi-kernel path; k_qgemm restructured to single-A-read
// (256 blocks, full-K LDS A, nb loop restaging B only). Scan = 256x8 chunks
// with 32-term truncated carry prefix (HW-validated in R4's mega, 0.43^32~2e-12).

#define GAMMA_F 0.9f
#define T_LEN 2048
#define D_DIM 256
#define B_DIM 16

typedef __attribute__((ext_vector_type(8))) short bf16x8;
typedef __attribute__((ext_vector_type(16))) float f32x16;

__device__ inline ushort f2bf(float f) {
    union { float f; unsigned u; } v; v.f = f;
    unsigned r = (v.u + 0x7FFFu + ((v.u >> 16) & 1u)) >> 16;  // RNE
    return (ushort)r;
}

// ---------- K1: prep — WqT, WkT (bf16 [n][k]) + wv_sum ----------
__global__ __launch_bounds__(256) void k_prep(const float* __restrict__ Wq,
                                              const float* __restrict__ Wk,
                                              const float* __restrict__ Wv,
                                              ushort* __restrict__ WqT,
                                              ushort* __restrict__ WkT,
                                              float* __restrict__ wv_sum) {
    int bid = blockIdx.x;
    int tid = threadIdx.x;
    if (bid < 32) {
        __shared__ float tile[64][68];
        const float* W = (bid < 16) ? Wq : Wk;
        ushort* WT = (bid < 16) ? WqT : WkT;
        int b = bid & 15;
        int k0 = (b & 3) * 64;
        int n0 = (b >> 2) * 64;
        int r = tid >> 4;            // 0..15
        int c4 = (tid & 15) * 4;     // 0..60
#pragma unroll
        for (int i = 0; i < 4; ++i) {
            float4 v = *(const float4*)(W + (size_t)(k0 + r + 16 * i) * D_DIM + n0 + c4);
            *(float4*)&tile[r + 16 * i][c4] = v;
        }
        __syncthreads();
        int n = tid >> 2;            // 0..63
        int j0 = (tid & 3) * 16;     // 0..48
        ushort tmp[16];
#pragma unroll
        for (int i = 0; i < 16; ++i) tmp[i] = f2bf(tile[j0 + i][n]);
        ushort* dst = WT + (size_t)(n0 + n) * D_DIM + k0 + j0;
#pragma unroll
        for (int i = 0; i < 16; ++i) dst[i] = tmp[i];
    } else {
        int j = (bid - 32) * 64 + (tid >> 2);
        int q = tid & 3;
        const float4* row4 = (const float4*)(Wv + (size_t)j * D_DIM + q * 64);
        float s = 0.f;
#pragma unroll
        for (int i = 0; i < 16; ++i) {
            float4 v = row4[i];
            s += v.x + v.y + v.z + v.w;
        }
        s += __shfl_xor(s, 1, 64);
        s += __shfl_xor(s, 2, 64);
        if (q == 0) wv_sum[j] = s;
    }
}

// ---------- K2: y (bf16) + xbf ----------
__global__ __launch_bounds__(256) void k_y(const float* __restrict__ x,
                                           const float* __restrict__ wv_sum,
                                           ushort* __restrict__ ybf,
                                           ushort* __restrict__ xbf) {
    int t = blockIdx.x;
    int d = threadIdx.x;
    float wvd = wv_sum[d];
    float xr[B_DIM];
#pragma unroll
    for (int b = 0; b < B_DIM; ++b)
        xr[b] = x[((size_t)b * T_LEN + t) * D_DIM + d];
#pragma unroll
    for (int b = 0; b < B_DIM; ++b)
        xbf[((size_t)b * T_LEN + t) * D_DIM + d] = f2bf(xr[b]);

    __shared__ float red[B_DIM][4];
    int wave = d >> 6, lane = d & 63;
#pragma unroll
    for (int b = 0; b < B_DIM; ++b) {
        float p = xr[b] * wvd;
        for (int o = 32; o > 0; o >>= 1) p += __shfl_down(p, o, 64);
        if (lane == 0) red[b][wave] = p;
    }
    __syncthreads();
    float yv = 0.f;
#pragma unroll
    for (int b = 0; b < B_DIM; ++b) {
        float wb = red[b][0] + red[b][1] + red[b][2] + red[b][3];
        yv += wb * xr[b];
    }
    ybf[(size_t)t * D_DIM + d] = f2bf(yv);
}

// ---------- K3: g = ybf @ WkT^T  (bf16 MFMA, 64x64 tile, LDS-staged) ----------
__global__ __launch_bounds__(256) void k_gmm(const ushort* __restrict__ ybf,
                                             const ushort* __restrict__ WkT,
                                             float* __restrict__ g) {
    __shared__ ushort As[32 * 64 * 8];   // 32 KB  [s2h][row^swz][8]
    __shared__ ushort Bs[32 * 64 * 8];   // 32 KB
    int mt = blockIdx.x >> 2;            // 0..31 (t tile)
    int nt = blockIdx.x & 3;             // 0..3  (n tile)
    int tid = threadIdx.x, lane = tid & 63, w = tid >> 6;
    int wr = w >> 1, wc = w & 1, l31 = lane & 31, lh = lane >> 5;

#pragma unroll
    for (int i = 0; i < 8; ++i) {
        int slot = tid + 256 * i;        // 0..2047
        int r = slot >> 5;               // 0..63
        int s2h = slot & 31;             // 0..31
        int rs = r ^ (s2h & 7);          // bank swizzle
        *(bf16x8*)&As[(s2h * 64 + rs) * 8] =
            *(const bf16x8*)&ybf[(size_t)(mt * 64 + r) * D_DIM + s2h * 8];
        *(bf16x8*)&Bs[(s2h * 64 + rs) * 8] =
            *(const bf16x8*)&WkT[(size_t)(nt * 64 + r) * D_DIM + s2h * 8];
    }
    __syncthreads();

    f32x16 acc;
#pragma unroll
    for (int e = 0; e < 16; ++e) acc[e] = 0.f;
#pragma unroll
    for (int s = 0; s < 16; ++s) {
        int s2h = s * 2 + lh;
        int ra = (wr * 32 + l31) ^ (s2h & 7);
        int rb = (wc * 32 + l31) ^ (s2h & 7);
        bf16x8 a = *(bf16x8*)&As[(s2h * 64 + ra) * 8];
        bf16x8 b = *(bf16x8*)&Bs[(s2h * 64 + rb) * 8];
        acc = __builtin_amdgcn_mfma_f32_32x32x16_bf16(a, b, acc, 0, 0, 0);
    }
#pragma unroll
    for (int reg = 0; reg < 16; ++reg) {
        int rr = (reg & 3) + 8 * (reg >> 2) + 4 * lh;
        g[(size_t)(mt * 64 + wr * 32 + rr) * D_DIM + nt * 64 + wc * 32 + l31] = acc[reg];
    }
}

// ---------- K4: local scan, 256 chunks of 8 ----------
__global__ void k_scanA(const float* __restrict__ g, float* __restrict__ loc,
                        float* __restrict__ carry) {
    int c = blockIdx.x;      // 0..255
    int d = threadIdx.x;     // 0..255
    float v[8];
#pragma unroll
    for (int j = 0; j < 8; ++j) {
        int t = c * 8 + j;
        v[j] = (t == 0) ? 0.f : g[(size_t)t * D_DIM + d];
    }
    float acc = 0.f;
#pragma unroll
    for (int j = 0; j < 8; ++j) {
        acc = GAMMA_F * acc + v[j];
        loc[(size_t)(c * 8 + j) * D_DIM + d] = acc;
    }
    carry[(size_t)c * D_DIM + d] = acc;
}

// ---------- K5: A[t] = loc + gamma^(o+1)*P[c] (P truncated, 32 terms); scatter ----------
__global__ __launch_bounds__(256) void k_S2P(const float* __restrict__ loc,
                                             const float* __restrict__ carry,
                                             float* __restrict__ S2) {
    int tp = blockIdx.x;
    int r = threadIdx.x;
    int src = (tp == 0) ? 1 : tp;           // S[0] = A[1]
    int c = src >> 3, o = src & 7;
    const float g8 = 0.43046721f;           // 0.9^8
    int j0 = c - 32; if (j0 < 0) j0 = 0;    // 0.43^32 ~ 2e-12: exact to f32
    float p = 0.f;
    for (int j = j0; j < c; ++j)
        p = p * g8 + carry[(size_t)j * D_DIM + r];
    const float log2g = -0.15200309344504995f;  // log2(0.9)
    float gp = exp2f((float)(o + 1) * log2g);
    float Aval = loc[(size_t)src * D_DIM + r] + gp * p;
    int trow = ((tp & 7) << 8) + r;
    int dcol = tp >> 3;
    S2[(size_t)trow * D_DIM + dcol] = Aval;
}

// ---------- K6: out = (xbf @ WqT^T) * S2 ----------
// 256 blocks (one per 128-row M tile). A staged to LDS ONCE for full K=256
// (64 KB); nb in {0,1} restages only B (64 KB). 3 barriers total.
__global__ __launch_bounds__(256) void k_qgemm(const ushort* __restrict__ xbf,
                                               const ushort* __restrict__ WqT,
                                               const float* __restrict__ S2,
                                               float* __restrict__ out) {
    __shared__ ushort As[32 * 128 * 8];   // 64 KB  [s2h][r][8]
    __shared__ ushort Bs[32 * 128 * 8];   // 64 KB
    int mb = blockIdx.x;                  // 0..255
    int tid = threadIdx.x;
    int lane = tid & 63, w = tid >> 6;
    int wr = w >> 1, wc = w & 1, l31 = lane & 31, lh = lane >> 5;
    int r = tid >> 1, h0 = tid & 1;

    // stage A, full K (s2h = kb*8 + h0*4 + j; k = s2h*8)
    const ushort* ag = xbf + (size_t)(mb * 128 + r) * D_DIM + h0 * 32;
#pragma unroll
    for (int kb = 0; kb < 4; ++kb)
#pragma unroll
        for (int j = 0; j < 4; ++j)
            *(bf16x8*)&As[((kb * 8 + h0 * 4 + j) * 128 + r) * 8] =
                *(const bf16x8*)(ag + kb * 64 + j * 8);

    int t_base = (mb & 15) * 128;
    size_t row_base = (size_t)mb * 128;

    for (int nb = 0; nb < 2; ++nb) {
        if (nb) __syncthreads();          // drain nb=0 readers of Bs
        const ushort* bg = WqT + (size_t)(nb * 128 + r) * D_DIM + h0 * 32;
#pragma unroll
        for (int kb = 0; kb < 4; ++kb)
#pragma unroll
            for (int j = 0; j < 4; ++j)
                *(bf16x8*)&Bs[((kb * 8 + h0 * 4 + j) * 128 + r) * 8] =
                    *(const bf16x8*)(bg + kb * 64 + j * 8);
        __syncthreads();                  // A (first iter) + B visible

        f32x16 acc[2][2];
#pragma unroll
        for (int i = 0; i < 2; ++i)
#pragma unroll
            for (int j = 0; j < 2; ++j)
#pragma unroll
                for (int e = 0; e < 16; ++e) acc[i][j][e] = 0.f;

#pragma unroll
        for (int s = 0; s < 16; ++s) {
            int c0 = (s * 2 + lh) * 128;
            bf16x8 a0 = *(bf16x8*)&As[(c0 + wr * 64 + l31) * 8];
            bf16x8 a1 = *(bf16x8*)&As[(c0 + wr * 64 + 32 + l31) * 8];
            bf16x8 b0 = *(bf16x8*)&Bs[(c0 + wc * 64 + l31) * 8];
            bf16x8 b1 = *(bf16x8*)&Bs[(c0 + wc * 64 + 32 + l31) * 8];
            acc[0][0] = __builtin_amdgcn_mfma_f32_32x32x16_bf16(a0, b0, acc[0][0], 0, 0, 0);
            acc[0][1] = __builtin_amdgcn_mfma_f32_32x32x16_bf16(a0, b1, acc[0][1], 0, 0, 0);
            acc[1][0] = __builtin_amdgcn_mfma_f32_32x32x16_bf16(a1, b0, acc[1][0], 0, 0, 0);
            acc[1][1] = __builtin_amdgcn_mfma_f32_32x32x16_bf16(a1, b1, acc[1][1], 0, 0, 0);
        }

#pragma unroll
        for (int mi = 0; mi < 2; ++mi) {
#pragma unroll
            for (int ni = 0; ni < 2; ++ni) {
                int gn = nb * 128 + wc * 64 + ni * 32 + l31;
#pragma unroll
                for (int reg = 0; reg < 16; ++reg) {
                    int rr = (reg & 3) + 8 * (reg >> 2) + 4 * lh;
                    int m = wr * 64 + mi * 32 + rr;
                    float s2v = S2[(size_t)(t_base + m) * D_DIM + gn];
                    out[(row_base + m) * D_DIM + gn] = acc[mi][ni][reg] * s2v;
                }
            }
        }
    }
}

extern "C" void kernel_launch(void* const* d_in, const int* in_sizes, int n_in,
                              void* d_out, int out_size, void* d_ws, size_t ws_size,
                              hipStream_t stream) {
    const float* x  = (const float*)d_in[0];
    const float* Wq = (const float*)d_in[1];
    const float* Wk = (const float*)d_in[2];
    const float* Wv = (const float*)d_in[3];
    float* out = (float*)d_out;

    // workspace layout
    float* ws = (float*)d_ws;
    float* g      = ws;                        // 524288 f
    float* loc    = g + 524288;                // 524288 f
    float* S2     = loc + 524288;              // 524288 f
    float* wv_sum = S2 + 524288;               // 256 f
    float* carry  = wv_sum + 256;              // 65536 f (256 chunks x 256)
    ushort* WqT   = (ushort*)(carry + 65536);  // 65536 us
    ushort* WkT   = WqT + 65536;               // 65536 us
    ushort* ybf   = WkT + 65536;               // 524288 us
    ushort* xbf   = ybf + 524288;              // 8388608 us

    k_prep<<<36, 256, 0, stream>>>(Wq, Wk, Wv, WqT, WkT, wv_sum);
    k_y<<<T_LEN, 256, 0, stream>>>(x, wv_sum, ybf, xbf);
    k_gmm<<<128, 256, 0, stream>>>(ybf, WkT, g);
    k_scanA<<<256, 256, 0, stream>>>(g, loc, carry);
    k_S2P<<<T_LEN, 256, 0, stream>>>(loc, carry, S2);
    k_qgemm<<<256, 256, 0, stream>>>(xbf, WqT, S2, out);
}